// Round 12
// baseline (558.995 us; speedup 1.0000x reference)
//
#include <hip/hip_runtime.h>
#include <math.h>

#define BB 32
#define TT 512
#define SS 1024
#define HH 1024

typedef __attribute__((ext_vector_type(8))) short short8;
typedef __attribute__((ext_vector_type(4))) float f32x4;
typedef __attribute__((ext_vector_type(4))) unsigned short u16x4;
typedef unsigned short u16;

__device__ __forceinline__ u16 f2h(float x) {
    union { float f; unsigned int u; } a; a.f = x;
    unsigned int u = a.u;
    return (u16)((u + 0x7fffu + ((u >> 16) & 1u)) >> 16);
}
__device__ __forceinline__ float h2f(u16 h) {
    union { unsigned int u; float f; } a; a.u = ((unsigned int)h) << 16;
    return a.f;
}

// async global->LDS, 16B per lane; LDS dest = wave-uniform base + lane*16.
__device__ __forceinline__ void gll16(const u16* g, u16* l) {
    __builtin_amdgcn_global_load_lds(
        (const __attribute__((address_space(1))) void*)g,
        (__attribute__((address_space(3))) void*)l, 16, 0, 0);
}

enum { E_F32 = 0, E_SPLIT = 1, E_TANH = 2, E_H = 3 };

struct Segs { const u16* a[4]; const u16* b[4]; };

// ---------------------------------------------------------------------------
// 128x256 bf16 NT GEMM, BK=32, 8 waves (2M x 4N, 64x64/wave), LDS 48KiB
// -> 2 blocks/CU co-resident (16 waves/CU = 4/SIMD): one block's MFMA covers
// the other's stage/vmcnt/barrier stalls (m114 TLP — the lever R5-R11's
// single-block schedules could not reach). All grids exactly 512 blocks.
// C = A' @ B'^T over K' = NSEG*1024 (Ootomo K'-extension, same numerics as
// R9: identical products, k-ascending accumulation -> bit-identical output).
// Per tile: stage(t+1) 3x gll16 -> 8x ds_read_b128 (swizzled, conflict-free
// 16-row frags) -> 16 MFMA 16x16x32 -> vmcnt(0) -> barrier.
// ---------------------------------------------------------------------------
template<int NSEG, int EPI>
__global__ __launch_bounds__(512, 4) void gemm2b(
    Segs sg, int ldA, int ldB, int zshift,
    long sA, long sB, long sC,
    const float* __restrict__ bias,
    float* __restrict__ Cf, u16* __restrict__ Ch, u16* __restrict__ Cl,
    int ldC)
{
    __shared__ u16 Abuf[2][128 * 32];   // 16 KiB
    __shared__ u16 Bbuf[2][256 * 32];   // 32 KiB

    const int tid = threadIdx.x;
    const int l = tid & 63, w = tid >> 6;
    const int wr = w >> 2, wc = w & 3;   // wave grid 2(M) x 4(N)
    const int fr = l & 15, g = l >> 4;

    // XCD-chunked decode (512 blocks, 64 per XCD)
    const int id = blockIdx.x;
    const int v = (id & 7) * 64 + (id >> 3);
    const int z = v >> zshift;
    const int rest = v & ((1 << zshift) - 1);
    const int bm = (rest >> 2) * 128;
    const int bn = (rest & 3) * 256;

    const u16* Aseg[4]; const u16* Bseg[4];
#pragma unroll
    for (int s = 0; s < NSEG; ++s) {
        Aseg[s] = sg.a[s] + (long)z * sA;
        Bseg[s] = sg.b[s] + (long)z * sB;
    }
    if (EPI == E_F32 || EPI == E_TANH) Cf += (long)z * sC;
    else { Ch += (long)z * sC; if (EPI == E_SPLIT) Cl += (long)z * sC; }

    f32x4 acc[4][4] = {};

    // ---- staging addressing ----
    // A: 512 chunks (128 rows x 4), 1/thread; B: 1024 chunks, 2/thread.
    const int srow = tid >> 2, sch = tid & 3;
    const int skc = sch ^ ((srow >> 1) & 3);     // row+128 keeps same swz
    const long grA  = (long)(bm + srow) * ldA + skc * 8;
    const long grB0 = (long)(bn + srow) * ldB + skc * 8;
    const long grB1 = (long)(bn + 128 + srow) * ldB + skc * 8;
    const int ldst0 = (tid & ~63) * 8;           // wave-uniform, u16 elems
    const int ldst1 = (512 + (tid & ~63)) * 8;

    auto stage = [&](int tile) {
        const int k0g = tile * 32;
        const int seg = k0g >> 10, kl = k0g & 1023;
        const int buf = tile & 1;
        gll16(Aseg[seg] + grA + kl, &Abuf[buf][ldst0]);
        gll16(Bseg[seg] + grB0 + kl, &Bbuf[buf][ldst0]);
        gll16(Bseg[seg] + grB1 + kl, &Bbuf[buf][ldst1]);
    };

    // ---- fragment read offsets (swizzled; 16-row frags -> conflict-free) ----
    int offA[4], offB[4];
#pragma unroll
    for (int fi = 0; fi < 4; ++fi) {
        const int r = wr * 64 + fi * 16 + fr;
        offA[fi] = (r * 4 + (g ^ ((r >> 1) & 3))) * 8;
    }
#pragma unroll
    for (int fj = 0; fj < 4; ++fj) {
        const int r = wc * 64 + fj * 16 + fr;
        offB[fj] = (r * 4 + (g ^ ((r >> 1) & 3))) * 8;
    }

    // prologue
    stage(0);
    asm volatile("s_waitcnt vmcnt(0)" ::: "memory");
    __builtin_amdgcn_s_barrier();

    const int NT = NSEG * 32;
    for (int t = 0; t < NT; ++t) {
        const int cur = t & 1;
        const bool nl = (t + 1 < NT);

        if (nl) stage(t + 1);

        short8 fa[4], fb[4];
        const u16* Ap = &Abuf[cur][0];
        const u16* Bp = &Bbuf[cur][0];
#pragma unroll
        for (int i = 0; i < 4; ++i) fa[i] = *(const short8*)&Ap[offA[i]];
#pragma unroll
        for (int j = 0; j < 4; ++j) fb[j] = *(const short8*)&Bp[offB[j]];
        __builtin_amdgcn_sched_barrier(0);

        __builtin_amdgcn_s_setprio(1);
#pragma unroll
        for (int i = 0; i < 4; ++i)
#pragma unroll
            for (int j = 0; j < 4; ++j)
                acc[i][j] = __builtin_amdgcn_mfma_f32_16x16x32_bf16(
                    fa[i], fb[j], acc[i][j], 0, 0, 0);
        __builtin_amdgcn_s_setprio(0);

        if (nl) { asm volatile("s_waitcnt vmcnt(0)" ::: "memory"); }
        __builtin_amdgcn_s_barrier();
    }

    // epilogue: frag D[row=g*4+r][col=fr]
#pragma unroll
    for (int mi = 0; mi < 4; ++mi) {
        const int row0 = bm + wr * 64 + mi * 16 + g * 4;
#pragma unroll
        for (int nj = 0; nj < 4; ++nj) {
            const int col = bn + wc * 64 + nj * 16 + fr;
            const float bv = (EPI == E_TANH) ? bias[col] : 0.0f;
#pragma unroll
            for (int r = 0; r < 4; ++r) {
                const float vv = acc[mi][nj][r];
                const long o = (long)(row0 + r) * ldC + col;
                if (EPI == E_TANH) {
                    const float e = __expf(2.0f * (vv + bv));
                    Cf[o] = 1.0f - 2.0f / (e + 1.0f);
                } else if (EPI == E_F32) {
                    Cf[o] = vv;
                } else if (EPI == E_SPLIT) {
                    const u16 h = f2h(vv);
                    Ch[o] = h; Cl[o] = f2h(vv - h2f(h));
                } else {
                    Ch[o] = f2h(vv);
                }
            }
        }
    }
}

// ---------------------------------------------------------------------------
// fp32 -> (hi, lo) bf16 splitter
// ---------------------------------------------------------------------------
__global__ __launch_bounds__(256) void split_f32(
    const float* __restrict__ in, u16* __restrict__ hi, u16* __restrict__ lo,
    long n4)
{
    long i = (long)blockIdx.x * blockDim.x + threadIdx.x;
    const long stride = (long)gridDim.x * blockDim.x;
    for (; i < n4; i += stride) {
        f32x4 v = *(const f32x4*)(in + i * 4);
        u16x4 h4, l4;
#pragma unroll
        for (int e = 0; e < 4; ++e) {
            u16 h_ = f2h(v[e]);
            h4[e] = h_; l4[e] = f2h(v[e] - h2f(h_));
        }
        *(u16x4*)(hi + i * 4) = h4;
        *(u16x4*)(lo + i * 4) = l4;
    }
}

// ---------------------------------------------------------------------------
// ench [B,S,H] bf16 -> encTh [B,H,S] bf16 (64x64 LDS tiles)
// ---------------------------------------------------------------------------
__global__ __launch_bounds__(256) void transpose_h(
    const u16* __restrict__ in, u16* __restrict__ out)
{
    __shared__ u16 t[64][72];
    const int z = blockIdx.z, sb = blockIdx.x * 64, hb = blockIdx.y * 64;
    const int c4 = (threadIdx.x & 15) * 4, r0 = threadIdx.x >> 4;
    const u16* src = in + ((long)z * SS + sb) * HH + hb;
#pragma unroll
    for (int i = 0; i < 4; ++i) {
        const int r = r0 + i * 16;
        u16x4 v = *(const u16x4*)(src + (long)r * HH + c4);
        t[c4 + 0][r] = v[0]; t[c4 + 1][r] = v[1];
        t[c4 + 2][r] = v[2]; t[c4 + 3][r] = v[3];
    }
    __syncthreads();
    u16* dst = out + ((long)z * HH + hb) * SS + sb;
#pragma unroll
    for (int i = 0; i < 4; ++i) {
        const int r = r0 + i * 16;                 // local h
        u16x4 o;
#pragma unroll
        for (int j = 0; j < 4; ++j) o[j] = t[r][c4 + j];
        *(u16x4*)(dst + (long)r * SS + c4) = o;
    }
}

// ---------------------------------------------------------------------------
// Mask + row softmax: scores fp32 in, P bf16(hi) out. One block per (b,t).
// ---------------------------------------------------------------------------
__global__ __launch_bounds__(256) void softmax_mask(
    const float* __restrict__ Sc, u16* __restrict__ Ph,
    const int* __restrict__ lens)
{
    const int row = blockIdx.x;
    const int b = row >> 9;             // / T (T=512)
    const int len = lens[b];
    const float* p = Sc + (long)row * SS;

    const int tid = threadIdx.x;
    const int s0 = tid * 4;
    f32x4 v = *(const f32x4*)(p + s0);
    float vals[4] = {v.x, v.y, v.z, v.w};

    float mx = -INFINITY;
#pragma unroll
    for (int j = 0; j < 4; ++j) {
        if (s0 + j >= len) vals[j] = -INFINITY;
        mx = fmaxf(mx, vals[j]);
    }
    for (int off = 32; off; off >>= 1) mx = fmaxf(mx, __shfl_xor(mx, off, 64));

    __shared__ float redm[4];
    __shared__ float reds[4];
    const int wave = tid >> 6, lane = tid & 63;
    if (lane == 0) redm[wave] = mx;
    __syncthreads();
    mx = fmaxf(fmaxf(redm[0], redm[1]), fmaxf(redm[2], redm[3]));

    float sum = 0.0f;
#pragma unroll
    for (int j = 0; j < 4; ++j) {
        vals[j] = __expf(vals[j] - mx);
        sum += vals[j];
    }
    for (int off = 32; off; off >>= 1) sum += __shfl_xor(sum, off, 64);
    if (lane == 0) reds[wave] = sum;
    __syncthreads();
    sum = reds[0] + reds[1] + reds[2] + reds[3];

    const float inv = 1.0f / sum;
    u16x4 o;
#pragma unroll
    for (int j = 0; j < 4; ++j) o[j] = f2h(vals[j] * inv);
    *(u16x4*)(Ph + (long)row * SS + s0) = o;
}

// ---------------------------------------------------------------------------
extern "C" void kernel_launch(void* const* d_in, const int* in_sizes, int n_in,
                              void* d_out, int out_size, void* d_ws, size_t ws_size,
                              hipStream_t stream)
{
    const float* query = (const float*)d_in[0];   // [B,T,H]
    const float* enc   = (const float*)d_in[1];   // [B,S,H]
    const int*   lens  = (const int*)d_in[2];     // [B]
    const float* W_in  = (const float*)d_in[3];   // [H,H]
    const float* W_out = (const float*)d_in[4];   // [H,2H]
    const float* b_out = (const float*)d_in[5];   // [H]
    float* out = (float*)d_out;

    const long MQ = (long)BB * TT;                // 16384

    u16* qh   = (u16*)d_ws;                       // [M,H]    32MiB
    u16* ql   = qh   + MQ * HH;                   //          32MiB
    u16* qwh  = ql   + MQ * HH;                   // [M,H]    32MiB
    u16* qwl  = qwh  + MQ * HH;                   //          32MiB
    u16* ench = qwl  + MQ * HH;                   // [B,S,H]  64MiB
    u16* encl = ench + (long)BB * SS * HH;        //          64MiB
    u16* ph   = encl + (long)BB * SS * HH;        // [M,S]    32MiB
    u16* wih  = ph   + MQ * SS;                   // [H,H]    2MiB
    u16* wil  = wih  + (long)HH * HH;
    u16* woh  = wil  + (long)HH * HH;             // [H,2H]   4MiB
    u16* wol  = woh  + (long)HH * 2 * HH;
    float* scores = (float*)(wol + (long)HH * 2 * HH);  // [M,S] fp32 64MiB
    u16* encTh = (u16*)scores;                    // overlays scores (after softmax)
    u16* ch   = ql;                               // overlays ql (dead after K1)

    // Pre-split fp32 operands -> bf16 hi/lo
    split_f32<<<2048, 256, 0, stream>>>(query, qh, ql, MQ * HH / 4);
    split_f32<<<512, 256, 0, stream>>>(W_in, wih, wil, (long)HH * HH / 4);
    split_f32<<<512, 256, 0, stream>>>(W_out, woh, wol, (long)HH * 2 * HH / 4);
    split_f32<<<2048, 256, 0, stream>>>(enc, ench, encl, (long)BB * SS * HH / 4);

    // K1: qw = query @ W_in^T  (3-product, K'=3072) -> split output
    // grid 512 = 128 Mtiles x 4 Ntiles (zshift 9)
    Segs s1 = {{qh, qh, ql, nullptr}, {wih, wil, wih, nullptr}};
    gemm2b<3, E_SPLIT><<<512, 512, 0, stream>>>(
        s1, HH, HH, 9, 0L, 0L, 0L, nullptr, nullptr, qwh, qwl, HH);

    // K2: scores[b] = qw[b] @ enc[b]^T  (3-product), 32 x (4M x 4N)
    Segs s2 = {{qwh, qwh, qwl, nullptr}, {ench, encl, ench, nullptr}};
    gemm2b<3, E_F32><<<512, 512, 0, stream>>>(
        s2, HH, HH, 4, (long)TT * HH, (long)SS * HH, (long)TT * SS,
        nullptr, scores, nullptr, nullptr, SS);

    // softmax + mask -> P (bf16 hi)
    softmax_mask<<<BB * TT, 256, 0, stream>>>(scores, ph, lens);

    // transpose ench -> encT (bf16), overlays scores (dead after softmax)
    transpose_h<<<dim3(16, 16, 32), 256, 0, stream>>>(ench, encTh);

    // K3: c[b] = P[b] @ enc[b]  via NT with B=encT  (1-product, K'=1024)
    Segs s3 = {{ph, nullptr, nullptr, nullptr}, {encTh, nullptr, nullptr, nullptr}};
    gemm2b<1, E_H><<<512, 512, 0, stream>>>(
        s3, SS, SS, 4, (long)TT * SS, (long)HH * SS, (long)TT * HH,
        nullptr, nullptr, ch, nullptr, HH);

    // K4: out = tanh([q|c] @ W_out^T + b)  (K'=4096)
    Segs s4 = {{qh, ch, qh, ch},
               {woh, woh + 1024, wol, wol + 1024}};
    gemm2b<4, E_TANH><<<512, 512, 0, stream>>>(
        s4, HH, 2 * HH, 9, 0L, 0L, 0L, b_out, out, nullptr, nullptr, HH);
}

// Round 13
// 476.853 us; speedup vs baseline: 1.1723x; 1.1723x over previous
//
#include <hip/hip_runtime.h>
#include <math.h>

#define BB 32
#define TT 512
#define SS 1024
#define HH 1024

typedef __attribute__((ext_vector_type(8))) short short8;
typedef __attribute__((ext_vector_type(4))) float f32x4;
typedef __attribute__((ext_vector_type(4))) unsigned short u16x4;
typedef unsigned short u16;

__device__ __forceinline__ u16 f2h(float x) {
    union { float f; unsigned int u; } a; a.f = x;
    unsigned int u = a.u;
    return (u16)((u + 0x7fffu + ((u >> 16) & 1u)) >> 16);
}
__device__ __forceinline__ float h2f(u16 h) {
    union { unsigned int u; float f; } a; a.u = ((unsigned int)h) << 16;
    return a.f;
}

// async global->LDS, 16B per lane; LDS dest = wave-uniform base + lane*16.
__device__ __forceinline__ void gll16(const u16* g, u16* l) {
    __builtin_amdgcn_global_load_lds(
        (const __attribute__((address_space(1))) void*)g,
        (__attribute__((address_space(3))) void*)l, 16, 0, 0);
}

enum { E_F32 = 0, E_SPLIT = 1, E_TANH = 2, E_H = 3 };

struct Segs { const u16* a[4]; const u16* b[4]; };

// ---------------------------------------------------------------------------
// 256x256 pipelined bf16 NT GEMM (R9 schedule — best measured of 6 schedule
// variants R5-R12, all 44+-2% MfmaUtil): C = A' @ B'^T over K' = NSEG*1024
// (Ootomo split as K'-extension). 512 thr = 8 waves (2M x 4N), BK=64,
// LDS 128KiB dbuf, 16x16x32 MFMA (32x32 shape regressed: 4-way chunk-slot
// bank conflicts, R11). Per phase: [stage half of t+1] [vmcnt(4) at ph2/ph4]
// [barrier] [prefetch NEXT phase's frags] [sched_barrier] [16 MFMA on regs
// prefetched last phase].
// ---------------------------------------------------------------------------
template<int NSEG, int EPI>
__global__ __launch_bounds__(512, 2) void gemm8(
    Segs sg, int ldA, int ldB, int zshift,
    long sA, long sB, long sC,
    const float* __restrict__ bias,
    float* __restrict__ Cf, u16* __restrict__ Ch, u16* __restrict__ Cl,
    int ldC)
{
    __shared__ u16 lds[2][2][2][256 * 32];   // [buf][A/B][khalf][row*32+k]

    const int tid = threadIdx.x;
    const int l = tid & 63, w = tid >> 6;
    const int wr = w >> 2, wc = w & 3;       // wave grid 2(M) x 4(N)
    const int fr = l & 15, g = l >> 4;

    // XCD-chunked block decode
    const int id = blockIdx.x;
    const int v = ((id & 7) << 5) | (id >> 3);
    const int z = v >> zshift;
    const int rest = v & ((1 << zshift) - 1);
    const int bm = (rest >> 2) * 256;
    const int bn = (rest & 3) * 256;

    const u16* Aseg[4]; const u16* Bseg[4];
#pragma unroll
    for (int s = 0; s < NSEG; ++s) {
        Aseg[s] = sg.a[s] + (long)z * sA;
        Bseg[s] = sg.b[s] + (long)z * sB;
    }
    if (EPI == E_F32 || EPI == E_TANH) Cf += (long)z * sC;
    else { Ch += (long)z * sC; if (EPI == E_SPLIT) Cl += (long)z * sC; }

    f32x4 acc[8][4] = {};

    // ---- staging addressing: chunk p = r*512 + tid; row=p>>2, ch=p&3 ----
    const int srow = tid >> 2, sch = tid & 3;
    const int skc = sch ^ ((srow >> 1) & 3);        // r-indep (128%8==0)
    const long grA0 = (long)(bm + srow) * ldA + skc * 8;
    const long grA1 = (long)(bm + 128 + srow) * ldA + skc * 8;
    const long grB0 = (long)(bn + srow) * ldB + skc * 8;
    const long grB1 = (long)(bn + 128 + srow) * ldB + skc * 8;
    const int ldst0 = (tid & ~63) * 8;              // wave-uniform, u16 elems
    const int ldst1 = (512 + (tid & ~63)) * 8;

    auto stage = [&](int tile, int kh, int tensor) {
        const int k0g = tile * 64 + kh * 32;
        const int seg = k0g >> 10, kl = k0g & 1023;
        u16* lb = &lds[tile & 1][tensor][kh][0];
        if (tensor) {
            const u16* b = Bseg[seg];
            gll16(b + grB0 + kl, lb + ldst0);
            gll16(b + grB1 + kl, lb + ldst1);
        } else {
            const u16* a = Aseg[seg];
            gll16(a + grA0 + kl, lb + ldst0);
            gll16(a + grA1 + kl, lb + ldst1);
        }
    };

    // ---- fragment read offsets (u16 elems within one khalf plane) ----
    int offA[8], offB[4];
#pragma unroll
    for (int k = 0; k < 8; ++k) {
        const int r = wr * 128 + k * 16 + fr;
        offA[k] = (r * 4 + (g ^ ((r >> 1) & 3))) * 8;
    }
#pragma unroll
    for (int j = 0; j < 4; ++j) {
        const int r = wc * 64 + j * 16 + fr;
        offB[j] = (r * 4 + (g ^ ((r >> 1) & 3))) * 8;
    }

    short8 faX[4], faY[4], fbA[4], fbB[4];

#define PFA(FA, BUF, KS, MH)                                                   \
    { const u16* pl = &lds[BUF][0][KS][0];                                     \
      _Pragma("unroll") for (int i_ = 0; i_ < 4; ++i_)                         \
          FA[i_] = *(const short8*)&pl[offA[(MH) * 4 + i_]]; }
#define PFB(FB, BUF, KS)                                                       \
    { const u16* pl = &lds[BUF][1][KS][0];                                     \
      _Pragma("unroll") for (int j_ = 0; j_ < 4; ++j_)                         \
          FB[j_] = *(const short8*)&pl[offB[j_]]; }
#define MFMA16(FA, FB, MH)                                                     \
    __builtin_amdgcn_s_setprio(1);                                             \
    _Pragma("unroll") for (int i_ = 0; i_ < 4; ++i_)                           \
        _Pragma("unroll") for (int j_ = 0; j_ < 4; ++j_)                       \
            acc[(MH) * 4 + i_][j_] = __builtin_amdgcn_mfma_f32_16x16x32_bf16(  \
                FA[i_], FB[j_], acc[(MH) * 4 + i_][j_], 0, 0, 0);              \
    __builtin_amdgcn_s_setprio(0);

    // prologue: stage tile 0, drain, barrier, prefetch ph1 frags
    stage(0, 0, 0); stage(0, 0, 1); stage(0, 1, 0); stage(0, 1, 1);
    asm volatile("s_waitcnt vmcnt(0)" ::: "memory");
    __builtin_amdgcn_s_barrier();
    PFB(fbA, 0, 0)
    PFA(faX, 0, 0, 0)
    __builtin_amdgcn_sched_barrier(0);

    const int NT = NSEG * 16;
    for (int t = 0; t < NT; ++t) {
        const int cur = t & 1, nxt = cur ^ 1;
        const bool nl = (t + 1 < NT);

        // ph1: rows0-3 x ks0 (faX,fbA); stage A-k0(t+1); pf faY<-ks0/MH1
        if (nl) stage(t + 1, 0, 0);
        __builtin_amdgcn_s_barrier();
        PFA(faY, cur, 0, 1)
        __builtin_amdgcn_sched_barrier(0);
        MFMA16(faX, fbA, 0)

        // ph2: rows4-7 x ks0 (faY,fbA); stage B-k0(t+1); vmcnt retires k1(t);
        //      pf fbB<-ks1, faX<-ks1/MH0
        if (nl) stage(t + 1, 0, 1);
        if (nl) { asm volatile("s_waitcnt vmcnt(4)" ::: "memory"); }
        else    { asm volatile("s_waitcnt vmcnt(0)" ::: "memory"); }
        __builtin_amdgcn_s_barrier();
        PFB(fbB, cur, 1)
        PFA(faX, cur, 1, 0)
        __builtin_amdgcn_sched_barrier(0);
        MFMA16(faY, fbA, 1)

        // ph3: rows0-3 x ks1 (faX,fbB); stage A-k1(t+1); pf faY<-ks1/MH1
        if (nl) stage(t + 1, 1, 0);
        __builtin_amdgcn_s_barrier();
        PFA(faY, cur, 1, 1)
        __builtin_amdgcn_sched_barrier(0);
        MFMA16(faX, fbB, 0)

        // ph4: rows4-7 x ks1 (faY,fbB); stage B-k1(t+1); vmcnt retires
        //      k0(t+1); pf fbA<-nxt/ks0, faX<-nxt/ks0/MH0
        if (nl) stage(t + 1, 1, 1);
        if (nl) { asm volatile("s_waitcnt vmcnt(4)" ::: "memory"); }
        __builtin_amdgcn_s_barrier();
        PFB(fbA, nxt, 0)
        PFA(faX, nxt, 0, 0)
        __builtin_amdgcn_sched_barrier(0);
        MFMA16(faY, fbB, 1)
    }
#undef PFA
#undef PFB
#undef MFMA16

    // epilogue: frag D[row=g*4+r][col=fr]
#pragma unroll
    for (int mi = 0; mi < 8; ++mi) {
        const int row0 = bm + wr * 128 + mi * 16 + g * 4;
#pragma unroll
        for (int nj = 0; nj < 4; ++nj) {
            const int col = bn + wc * 64 + nj * 16 + fr;
            const float bv = (EPI == E_TANH) ? bias[col] : 0.0f;
#pragma unroll
            for (int r = 0; r < 4; ++r) {
                const float vv = acc[mi][nj][r];
                const long o = (long)(row0 + r) * ldC + col;
                if (EPI == E_TANH) {
                    const float e = __expf(2.0f * (vv + bv));
                    Cf[o] = 1.0f - 2.0f / (e + 1.0f);
                } else if (EPI == E_F32) {
                    Cf[o] = vv;
                } else if (EPI == E_SPLIT) {
                    const u16 h = f2h(vv);
                    Ch[o] = h; Cl[o] = f2h(vv - h2f(h));
                } else {
                    Ch[o] = f2h(vv);
                }
            }
        }
    }
}

// ---------------------------------------------------------------------------
// fp32 -> (hi, lo) bf16 splitter
// ---------------------------------------------------------------------------
__global__ __launch_bounds__(256) void split_f32(
    const float* __restrict__ in, u16* __restrict__ hi, u16* __restrict__ lo,
    long n4)
{
    long i = (long)blockIdx.x * blockDim.x + threadIdx.x;
    const long stride = (long)gridDim.x * blockDim.x;
    for (; i < n4; i += stride) {
        f32x4 v = *(const f32x4*)(in + i * 4);
        u16x4 h4, l4;
#pragma unroll
        for (int e = 0; e < 4; ++e) {
            u16 h_ = f2h(v[e]);
            h4[e] = h_; l4[e] = f2h(v[e] - h2f(h_));
        }
        *(u16x4*)(hi + i * 4) = h4;
        *(u16x4*)(lo + i * 4) = l4;
    }
}

// ---------------------------------------------------------------------------
// Fused enc prep: enc [B,S,H] fp32 -> ench/encl [B,S,H] bf16 + encTh [B,H,S]
// bf16 in ONE pass (64x64 LDS tiles). Saves the 64MiB ench re-read +
// one launch vs split_f32 + transpose_h. Values bit-identical (same f2h).
// ---------------------------------------------------------------------------
__global__ __launch_bounds__(256) void split_enc_fused(
    const float* __restrict__ in, u16* __restrict__ hi, u16* __restrict__ lo,
    u16* __restrict__ outT)
{
    __shared__ u16 t[64][72];
    const int z = blockIdx.z, sb = blockIdx.x * 64, hb = blockIdx.y * 64;
    const int c4 = (threadIdx.x & 15) * 4, r0 = threadIdx.x >> 4;
    const float* src = in + ((long)z * SS + sb) * HH + hb;
    u16* dhi = hi + ((long)z * SS + sb) * HH + hb;
    u16* dlo = lo + ((long)z * SS + sb) * HH + hb;
#pragma unroll
    for (int i = 0; i < 4; ++i) {
        const int r = r0 + i * 16;                 // local s
        f32x4 v = *(const f32x4*)(src + (long)r * HH + c4);
        u16x4 h4, l4;
#pragma unroll
        for (int j = 0; j < 4; ++j) {
            u16 h_ = f2h(v[j]);
            h4[j] = h_; l4[j] = f2h(v[j] - h2f(h_));
        }
        *(u16x4*)(dhi + (long)r * HH + c4) = h4;
        *(u16x4*)(dlo + (long)r * HH + c4) = l4;
        t[c4 + 0][r] = h4[0]; t[c4 + 1][r] = h4[1];
        t[c4 + 2][r] = h4[2]; t[c4 + 3][r] = h4[3];
    }
    __syncthreads();
    u16* dst = outT + ((long)z * HH + hb) * SS + sb;
#pragma unroll
    for (int i = 0; i < 4; ++i) {
        const int r = r0 + i * 16;                 // local h
        u16x4 o;
#pragma unroll
        for (int j = 0; j < 4; ++j) o[j] = t[r][c4 + j];
        *(u16x4*)(dst + (long)r * SS + c4) = o;
    }
}

// ---------------------------------------------------------------------------
// ench [B,S,H] bf16 -> encTh [B,H,S] bf16 (fallback path if ws too small)
// ---------------------------------------------------------------------------
__global__ __launch_bounds__(256) void transpose_h(
    const u16* __restrict__ in, u16* __restrict__ out)
{
    __shared__ u16 t[64][72];
    const int z = blockIdx.z, sb = blockIdx.x * 64, hb = blockIdx.y * 64;
    const int c4 = (threadIdx.x & 15) * 4, r0 = threadIdx.x >> 4;
    const u16* src = in + ((long)z * SS + sb) * HH + hb;
#pragma unroll
    for (int i = 0; i < 4; ++i) {
        const int r = r0 + i * 16;
        u16x4 v = *(const u16x4*)(src + (long)r * HH + c4);
        t[c4 + 0][r] = v[0]; t[c4 + 1][r] = v[1];
        t[c4 + 2][r] = v[2]; t[c4 + 3][r] = v[3];
    }
    __syncthreads();
    u16* dst = out + ((long)z * HH + hb) * SS + sb;
#pragma unroll
    for (int i = 0; i < 4; ++i) {
        const int r = r0 + i * 16;                 // local h
        u16x4 o;
#pragma unroll
        for (int j = 0; j < 4; ++j) o[j] = t[r][c4 + j];
        *(u16x4*)(dst + (long)r * SS + c4) = o;
    }
}

// ---------------------------------------------------------------------------
// Mask + row softmax: scores fp32 in, P bf16(hi) out. One block per (b,t).
// ---------------------------------------------------------------------------
__global__ __launch_bounds__(256) void softmax_mask(
    const float* __restrict__ Sc, u16* __restrict__ Ph,
    const int* __restrict__ lens)
{
    const int row = blockIdx.x;
    const int b = row >> 9;             // / T (T=512)
    const int len = lens[b];
    const float* p = Sc + (long)row * SS;

    const int tid = threadIdx.x;
    const int s0 = tid * 4;
    f32x4 v = *(const f32x4*)(p + s0);
    float vals[4] = {v.x, v.y, v.z, v.w};

    float mx = -INFINITY;
#pragma unroll
    for (int j = 0; j < 4; ++j) {
        if (s0 + j >= len) vals[j] = -INFINITY;
        mx = fmaxf(mx, vals[j]);
    }
    for (int off = 32; off; off >>= 1) mx = fmaxf(mx, __shfl_xor(mx, off, 64));

    __shared__ float redm[4];
    __shared__ float reds[4];
    const int wave = tid >> 6, lane = tid & 63;
    if (lane == 0) redm[wave] = mx;
    __syncthreads();
    mx = fmaxf(fmaxf(redm[0], redm[1]), fmaxf(redm[2], redm[3]));

    float sum = 0.0f;
#pragma unroll
    for (int j = 0; j < 4; ++j) {
        vals[j] = __expf(vals[j] - mx);
        sum += vals[j];
    }
    for (int off = 32; off; off >>= 1) sum += __shfl_xor(sum, off, 64);
    if (lane == 0) reds[wave] = sum;
    __syncthreads();
    sum = reds[0] + reds[1] + reds[2] + reds[3];

    const float inv = 1.0f / sum;
    u16x4 o;
#pragma unroll
    for (int j = 0; j < 4; ++j) o[j] = f2h(vals[j] * inv);
    *(u16x4*)(Ph + (long)row * SS + s0) = o;
}

// ---------------------------------------------------------------------------
extern "C" void kernel_launch(void* const* d_in, const int* in_sizes, int n_in,
                              void* d_out, int out_size, void* d_ws, size_t ws_size,
                              hipStream_t stream)
{
    const float* query = (const float*)d_in[0];   // [B,T,H]
    const float* enc   = (const float*)d_in[1];   // [B,S,H]
    const int*   lens  = (const int*)d_in[2];     // [B]
    const float* W_in  = (const float*)d_in[3];   // [H,H]
    const float* W_out = (const float*)d_in[4];   // [H,2H]
    const float* b_out = (const float*)d_in[5];   // [H]
    float* out = (float*)d_out;

    const long MQ = (long)BB * TT;                // 16384

    u16* qh   = (u16*)d_ws;                       // [M,H]    32MiB
    u16* ql   = qh   + MQ * HH;                   //          32MiB
    u16* qwh  = ql   + MQ * HH;                   // [M,H]    32MiB
    u16* qwl  = qwh  + MQ * HH;                   //          32MiB
    u16* ench = qwl  + MQ * HH;                   // [B,S,H]  64MiB
    u16* encl = ench + (long)BB * SS * HH;        //          64MiB
    u16* ph   = encl + (long)BB * SS * HH;        // [M,S]    32MiB
    u16* wih  = ph   + MQ * SS;                   // [H,H]    2MiB
    u16* wil  = wih  + (long)HH * HH;
    u16* woh  = wil  + (long)HH * HH;             // [H,2H]   4MiB
    u16* wol  = woh  + (long)HH * 2 * HH;
    float* scores = (float*)(wol + (long)HH * 2 * HH);  // [M,S] fp32 64MiB
    u16* ch   = ql;                               // overlays ql (dead after K1)

    // Fused path needs a dedicated encT region AFTER scores (+64MiB).
    u16* encT_ded = (u16*)(scores + MQ * SS);
    const size_t need_fused =
        (size_t)((u16*)(scores + MQ * SS) - (u16*)d_ws) * 2 + (size_t)BB * HH * SS * 2;
    const bool fused = (ws_size >= need_fused);
    u16* encTh = fused ? encT_ded : (u16*)scores;  // fallback overlays scores

    // Pre-split fp32 operands -> bf16 hi/lo
    split_f32<<<2048, 256, 0, stream>>>(query, qh, ql, MQ * HH / 4);
    split_f32<<<512, 256, 0, stream>>>(W_in, wih, wil, (long)HH * HH / 4);
    split_f32<<<512, 256, 0, stream>>>(W_out, woh, wol, (long)HH * 2 * HH / 4);
    if (fused) {
        // enc: split + transpose in one pass (encTh lives past scores)
        split_enc_fused<<<dim3(16, 16, 32), 256, 0, stream>>>(
            enc, ench, encl, encTh);
    } else {
        split_f32<<<2048, 256, 0, stream>>>(enc, ench, encl,
                                            (long)BB * SS * HH / 4);
    }

    // K1: qw = query @ W_in^T  (3-product, K'=3072) -> split output
    Segs s1 = {{qh, qh, ql, nullptr}, {wih, wil, wih, nullptr}};
    gemm8<3, E_SPLIT><<<256, 512, 0, stream>>>(
        s1, HH, HH, 8, 0L, 0L, 0L, nullptr, nullptr, qwh, qwl, HH);

    // K2: scores[b] = qw[b] @ enc[b]^T  (3-product, K'=3072), 32 batches
    Segs s2 = {{qwh, qwh, qwl, nullptr}, {ench, encl, ench, nullptr}};
    gemm8<3, E_F32><<<256, 512, 0, stream>>>(
        s2, HH, HH, 3, (long)TT * HH, (long)SS * HH, (long)TT * SS,
        nullptr, scores, nullptr, nullptr, SS);

    // softmax + mask -> P (bf16 hi)
    softmax_mask<<<BB * TT, 256, 0, stream>>>(scores, ph, lens);

    // Fallback only: transpose ench -> encTh (overlaying dead scores)
    if (!fused) {
        transpose_h<<<dim3(16, 16, 32), 256, 0, stream>>>(ench, encTh);
    }

    // K3: c[b] = P[b] @ enc[b]  via NT with B=encT  (1-product, K'=1024)
    Segs s3 = {{ph, nullptr, nullptr, nullptr}, {encTh, nullptr, nullptr, nullptr}};
    gemm8<1, E_H><<<256, 512, 0, stream>>>(
        s3, SS, SS, 3, (long)TT * SS, (long)HH * SS, (long)TT * HH,
        nullptr, nullptr, ch, nullptr, HH);

    // K4: out = tanh([q|c] @ W_out^T + b)  (K'=4096)
    Segs s4 = {{qh, ch, qh, ch},
               {woh, woh + 1024, wol, wol + 1024}};
    gemm8<4, E_TANH><<<256, 512, 0, stream>>>(
        s4, HH, 2 * HH, 8, 0L, 0L, 0L, b_out, out, nullptr, nullptr, HH);
}